// Round 2
// baseline (495.050 us; speedup 1.0000x reference)
//
#include <hip/hip_runtime.h>

// out[b] = mean_x( 0.5 - 0.5*tanh((x - bins[b]) * 2/bw) ), bw = 1/16,
//          bins[b] = -2 + bw*b, b in [0,64)
// = mean_x sigma(4*(b - t)), t = (x+2)*16  (bin coordinate), sigma = logistic.
//
// Sufficient statistic: fine histogram of t, cell = 1/64 bin, t in [-5, 69):
//   f = floor(x*1024 + 2368), clamped to [0, 4736).
// Per-bin fold (done inside the hist kernel, per block):
//   f <  64b         : sigma >= 1 - 2e-9  -> counts as exactly 1 (prefix count)
//   f in [64b,64b+640): sigma = sig[j], j = f - 64b, z = (319.5 - j)/16
//   f >= 64b + 640   : sigma <= 2e-9     -> 0
// sig[] depends only on j -> one shared table serves all bins/blocks.
// Block partials accumulated into 64 global u64 fixed-point (2^20) counters
// (native integer atomics; avoids fp-atomic CAS path and the 4.8M-atomic
// global-hist flush of the original version).

#define NCELLS   (74 * 64)      // 4736
#define NBINS    64
#define NGROUPS  74
#define WIN      640            // +/-5 bins of cells
#define HIST_BLOCKS  1024
#define HIST_THREADS 512
#define FIX_SCALE 1048576.0     // 2^20

typedef float floatv4 __attribute__((ext_vector_type(4)));

__global__ void __launch_bounds__(HIST_THREADS)
hist_fold_kernel(const float* __restrict__ x,
                 unsigned long long* __restrict__ gacc, int n)
{
    __shared__ unsigned hist[NCELLS];
    __shared__ float    sig[WIN];
    __shared__ unsigned G[NGROUPS];   // 64-cell group sums
    __shared__ unsigned P[NBINS];     // prefix counts at cell 64*b

    const int tid = threadIdx.x;

    for (int i = tid; i < NCELLS; i += HIST_THREADS) hist[i] = 0u;
    for (int j = tid; j < WIN; j += HIST_THREADS) {
        float z = (319.5f - (float)j) * 0.0625f;
        sig[j] = 1.0f / (1.0f + __expf(-z));
    }
    __syncthreads();

    const int n4 = n >> 2;
    const floatv4* __restrict__ x4 = (const floatv4*)x;
    const int gid    = blockIdx.x * HIST_THREADS + tid;
    const int stride = gridDim.x * HIST_THREADS;

    // (int) cast == floor for the in-range case; negatives clamp to 0 either way.
#define BUMP1(val) do {                                   \
        int f = (int)fmaf((val), 1024.0f, 2368.0f);       \
        f = min(max(f, 0), NCELLS - 1);                   \
        atomicAdd(&hist[f], 1u);                          \
    } while (0)
#define BUMP4(v) do { BUMP1((v).x); BUMP1((v).y); BUMP1((v).z); BUMP1((v).w); } while (0)

    // 4-deep unrolled stream: 4 KB in flight per wave (MLP to cover HBM latency)
    int i = gid;
    for (; i + 3 * stride < n4; i += 4 * stride) {
        floatv4 a = __builtin_nontemporal_load(&x4[i]);
        floatv4 b = __builtin_nontemporal_load(&x4[i + stride]);
        floatv4 c = __builtin_nontemporal_load(&x4[i + 2 * stride]);
        floatv4 d = __builtin_nontemporal_load(&x4[i + 3 * stride]);
        BUMP4(a); BUMP4(b); BUMP4(c); BUMP4(d);
    }
    for (; i < n4; i += stride) {
        floatv4 a = __builtin_nontemporal_load(&x4[i]);
        BUMP4(a);
    }
    if (blockIdx.x == 0) {          // scalar tail (n % 4)
        int tail = n & 3;
        if (tid < tail) { float v = x[(n4 << 2) + tid]; BUMP1(v); }
    }
    __syncthreads();

    const int wave = tid >> 6;
    const int lane = tid & 63;

    // group sums: wave-parallel, conflict-free (64 consecutive cells per read)
    for (int g = wave; g < NGROUPS; g += HIST_THREADS / 64) {
        unsigned v = hist[(g << 6) + lane];
        #pragma unroll
        for (int o = 32; o; o >>= 1) v += __shfl_xor(v, o);
        if (lane == 0) G[g] = v;
    }
    __syncthreads();

    if (tid < NBINS) {              // P[b] = count of cells f < 64*b
        unsigned p = 0;
        for (int g = 0; g < tid; ++g) p += G[g];
        P[tid] = p;
    }
    __syncthreads();

    // fold: wave w handles bins 8w..8w+7; lanes read consecutive cells (no bank conflicts)
    #pragma unroll
    for (int bi = 0; bi < 8; ++bi) {
        const int b = (wave << 3) + bi;
        float ws = 0.0f;
        const int base = (b << 6) + lane;
        #pragma unroll
        for (int p = 0; p < 10; ++p)
            ws += (float)hist[base + (p << 6)] * sig[(p << 6) + lane];
        #pragma unroll
        for (int o = 32; o; o >>= 1) ws += __shfl_xor(ws, o);
        if (lane == 0) {
            unsigned long long s = ((unsigned long long)P[b] << 20)
                                 + (unsigned long long)((double)ws * FIX_SCALE + 0.5);
            atomicAdd(&gacc[b], s);   // native u64 add, 64 per block
        }
    }
#undef BUMP1
#undef BUMP4
}

__global__ void __launch_bounds__(64)
finalize_kernel(const unsigned long long* __restrict__ gacc,
                float* __restrict__ out, double inv)
{
    const int b = threadIdx.x;
    out[b] = (float)((double)gacc[b] * inv);
}

extern "C" void kernel_launch(void* const* d_in, const int* in_sizes, int n_in,
                              void* d_out, int out_size, void* d_ws, size_t ws_size,
                              hipStream_t stream)
{
    const float* x = (const float*)d_in[0];
    const int n = in_sizes[0];
    unsigned long long* gacc = (unsigned long long*)d_ws;

    // d_ws is re-poisoned to 0xAA before every call; zero only the 512 B we use.
    (void)hipMemsetAsync(d_ws, 0, NBINS * sizeof(unsigned long long), stream);

    hist_fold_kernel<<<HIST_BLOCKS, HIST_THREADS, 0, stream>>>(x, gacc, n);
    finalize_kernel<<<1, 64, 0, stream>>>(gacc, (float*)d_out,
                                          1.0 / ((double)n * FIX_SCALE));
}

// Round 3
// 377.796 us; speedup vs baseline: 1.3104x; 1.3104x over previous
//
#include <hip/hip_runtime.h>

// out[b] = mean_x( 0.5 - 0.5*tanh((x - bins[b]) * 2/bw) ), bw = 1/16,
//          bins[b] = -2 + bw*b, b in [0,64)
// = mean_x sigma(4*(b - t)), t = (x+2)*16  (bin coordinate), sigma = logistic.
//
// Sufficient statistic: fine histogram of t, cell = 1/64 bin, t in [-5, 69):
//   f = floor(x*1024 + 2368), clamped to [0, 4736).
// Per-bin fold (inside the hist kernel, per block):
//   f <  64b          : sigma >= 1 - 2e-9  -> exactly 1 (prefix count)
//   f in [64b,64b+640): sigma = sig(j), j = f - 64b, z = (319.5 - j)/16
//   f >= 64b + 640    : sigma <= 2e-9     -> 0
// Per-block partials are WRITTEN (not atomically added) to part[bin][block];
// finalize sums them. No workspace zeroing needed, no global atomics.

#define NCELLS   (74 * 64)      // 4736
#define NBINS    64
#define NGROUPS  74
#define HIST_BLOCKS  2048
#define HIST_THREADS 256

typedef float floatv4 __attribute__((ext_vector_type(4)));

__global__ void __launch_bounds__(HIST_THREADS, 8)
hist_fold_kernel(const float* __restrict__ x,
                 double* __restrict__ part, int n)
{
    __shared__ unsigned hist[NCELLS];
    __shared__ unsigned G[NGROUPS];   // 64-cell group sums
    __shared__ unsigned P[NBINS];     // prefix counts at cell 64*b

    const int tid = threadIdx.x;

    for (int i = tid; i < NCELLS; i += HIST_THREADS) hist[i] = 0u;
    __syncthreads();

    const int n4 = n >> 2;
    const floatv4* __restrict__ x4 = (const floatv4*)x;
    const int stride = HIST_BLOCKS * HIST_THREADS;
    int i = blockIdx.x * HIST_THREADS + tid;

    // (int) cast == floor for the in-range case; negatives clamp to 0 either way.
#define BUMP1(val) do {                                   \
        int f = (int)fmaf((val), 1024.0f, 2368.0f);       \
        f = min(max(f, 0), NCELLS - 1);                   \
        atomicAdd(&hist[f], 1u);                          \
    } while (0)
#define BUMP4(v) do { BUMP1((v).x); BUMP1((v).y); BUMP1((v).z); BUMP1((v).w); } while (0)

    // Register double-buffer: issue group k+1's 4 loads BEFORE consuming group k,
    // so 8 wave-loads are in flight at the handoff (latency hidden under atomics).
    bool have = (i + 3 * stride < n4);
    floatv4 c0, c1, c2, c3;
    if (have) {
        c0 = x4[i]; c1 = x4[i + stride]; c2 = x4[i + 2 * stride]; c3 = x4[i + 3 * stride];
    }
    while (have) {
        const int j = i + 4 * stride;
        const bool nhave = (j + 3 * stride < n4);
        floatv4 n0, n1, n2, n3;
        if (nhave) {
            n0 = x4[j]; n1 = x4[j + stride]; n2 = x4[j + 2 * stride]; n3 = x4[j + 3 * stride];
        }
        BUMP4(c0); BUMP4(c1); BUMP4(c2); BUMP4(c3);
        c0 = n0; c1 = n1; c2 = n2; c3 = n3;
        i = j; have = nhave;
    }
    for (; i < n4; i += stride) {      // remainder groups (single-buffered)
        floatv4 a = x4[i];
        BUMP4(a);
    }
    if (blockIdx.x == 0) {             // scalar tail (n % 4)
        int tail = n & 3;
        if (tid < tail) { float v = x[(n4 << 2) + tid]; BUMP1(v); }
    }
    __syncthreads();

    const int wave = tid >> 6;
    const int lane = tid & 63;

    // sigma weights in registers: sig_r[p] for j = 64p + lane (shared by all bins)
    float sig_r[10];
    #pragma unroll
    for (int p = 0; p < 10; ++p) {
        float z = (319.5f - (float)((p << 6) + lane)) * 0.0625f;
        sig_r[p] = 1.0f / (1.0f + __expf(-z));
    }

    // group sums: wave-parallel, conflict-free (64 consecutive cells per read)
    for (int g = wave; g < NGROUPS; g += HIST_THREADS / 64) {
        unsigned v = hist[(g << 6) + lane];
        #pragma unroll
        for (int o = 32; o; o >>= 1) v += __shfl_xor(v, o);
        if (lane == 0) G[g] = v;
    }
    __syncthreads();

    if (tid < NBINS) {                 // P[b] = count of cells f < 64*b
        unsigned p = 0;
        for (int g = 0; g < tid; ++g) p += G[g];
        P[tid] = p;
    }
    __syncthreads();

    // fold: wave w handles bins 16w..16w+15; lanes read consecutive cells
    #pragma unroll
    for (int bi = 0; bi < 16; ++bi) {
        const int b = (wave << 4) + bi;
        float ws = 0.0f;
        const int base = (b << 6) + lane;
        #pragma unroll
        for (int p = 0; p < 10; ++p)
            ws += (float)hist[base + (p << 6)] * sig_r[p];
        #pragma unroll
        for (int o = 32; o; o >>= 1) ws += __shfl_xor(ws, o);
        if (lane == 0)
            part[(b << 11) + blockIdx.x] = (double)P[b] + (double)ws;
    }
#undef BUMP1
#undef BUMP4
}

__global__ void __launch_bounds__(256)
finalize_kernel(const double* __restrict__ part,
                float* __restrict__ out, double invN)
{
    const int b = blockIdx.x;          // 64 blocks, one per output bin
    const int tid = threadIdx.x;
    double s = 0.0;
    for (int j = tid; j < HIST_BLOCKS; j += 256)
        s += part[(b << 11) + j];
    __shared__ double sd[256];
    sd[tid] = s;
    __syncthreads();
    for (int ofs = 128; ofs > 0; ofs >>= 1) {
        if (tid < ofs) sd[tid] += sd[tid + ofs];
        __syncthreads();
    }
    if (tid == 0) out[b] = (float)(sd[0] * invN);
}

extern "C" void kernel_launch(void* const* d_in, const int* in_sizes, int n_in,
                              void* d_out, int out_size, void* d_ws, size_t ws_size,
                              hipStream_t stream)
{
    const float* x = (const float*)d_in[0];
    const int n = in_sizes[0];
    double* part = (double*)d_ws;      // 64 bins x 2048 blocks x 8 B = 1 MB
    // part is fully overwritten by hist_fold_kernel each call -> no memset needed.

    hist_fold_kernel<<<HIST_BLOCKS, HIST_THREADS, 0, stream>>>(x, part, n);
    finalize_kernel<<<NBINS, 256, 0, stream>>>(part, (float*)d_out,
                                               1.0 / (double)n);
}

// Round 5
// 368.175 us; speedup vs baseline: 1.3446x; 1.0261x over previous
//
#include <hip/hip_runtime.h>

// out[b] = mean_x( 0.5 - 0.5*tanh((x - bins[b]) * 2/bw) ), bw = 1/16,
//          bins[b] = -2 + bw*b, b in [0,64)
// = mean_x sigma(4*(b - t)), t = (x+2)*16  (bin coordinate), sigma = logistic.
//
// Sufficient statistic: fine histogram of t, cell = 1/64 bin, t in [-5, 69):
//   f = floor(x*1024 + 2368), clamped to [0, 4736).
// Per-bin fold (inside the hist kernel, per block):
//   f <  64b          : sigma >= 1 - 2e-9  -> exactly 1 (prefix count)
//   f in [64b,64b+640): sigma = sig(j), j = f - 64b, z = (319.5 - j)/16
//   f >= 64b + 640    : sigma <= 2e-9     -> 0
// Per-block partials are WRITTEN (not atomically added) to part[bin][block];
// finalize sums them. No workspace zeroing, no global atomics.
//
// Memory schedule: each wave owns contiguous 32 KB tiles (2048 float4).
// 8 groups/tile, 4 x 1KB unit-stride loads per group, software-pipelined
// depth 3 (8-12 loads in flight through the consume phase).
// __launch_bounds__(256,8) pins VGPR <= 64 so 32 waves/CU stay resident.

#define NCELLS   (74 * 64)      // 4736
#define NBINS    64
#define NGROUPS  74
#define HIST_BLOCKS  2048
#define HIST_THREADS 256
#define F4_PER_WAVE  2048       // 32 KB tile per wave
#define NWAVES   (HIST_BLOCKS * HIST_THREADS / 64)

typedef float floatv4 __attribute__((ext_vector_type(4)));

__global__ void __launch_bounds__(HIST_THREADS, 8)
hist_fold_kernel(const float* __restrict__ x,
                 double* __restrict__ part, int n)
{
    __shared__ unsigned hist[NCELLS];
    __shared__ unsigned G[NGROUPS];   // 64-cell group sums
    __shared__ unsigned P[NBINS];     // prefix counts at cell 64*b

    const int tid = threadIdx.x;

    for (int i = tid; i < NCELLS; i += HIST_THREADS) hist[i] = 0u;
    __syncthreads();

    const int n4 = n >> 2;
    const floatv4* __restrict__ x4 = (const floatv4*)x;
    const int lane  = tid & 63;
    const int gwave = ((blockIdx.x * HIST_THREADS) + tid) >> 6;

    // (int) cast == floor for the in-range case; negatives clamp to 0 either way.
#define BUMP1(val) do {                                   \
        int f = (int)fmaf((val), 1024.0f, 2368.0f);       \
        f = min(max(f, 0), NCELLS - 1);                   \
        atomicAdd(&hist[f], 1u);                          \
    } while (0)
#define BUMP4(v) do { BUMP1((v).x); BUMP1((v).y); BUMP1((v).z); BUMP1((v).w); } while (0)

    for (int base = gwave * F4_PER_WAVE; base < n4; base += NWAVES * F4_PER_WAVE) {
        if (base + F4_PER_WAVE <= n4) {
            // fast path: whole 32 KB tile in range, depth-3 pipeline
            const floatv4* __restrict__ p = x4 + base + lane;
            floatv4 A0,A1,A2,A3, B0,B1,B2,B3, C0,C1,C2,C3;
#define ISSUE(S, g) do { S##0 = p[(g)*256]; S##1 = p[(g)*256+64]; \
                         S##2 = p[(g)*256+128]; S##3 = p[(g)*256+192]; } while (0)
#define CONSUME(S) do { BUMP4(S##0); BUMP4(S##1); BUMP4(S##2); BUMP4(S##3); } while (0)
            ISSUE(A, 0); ISSUE(B, 1); ISSUE(C, 2);
            CONSUME(A); ISSUE(A, 3);
            CONSUME(B); ISSUE(B, 4);
            CONSUME(C); ISSUE(C, 5);
            CONSUME(A); ISSUE(A, 6);
            CONSUME(B); ISSUE(B, 7);
            CONSUME(C);
            CONSUME(A);
            CONSUME(B);
#undef ISSUE
#undef CONSUME
        } else {
            // edge tile: per-load bounds check (at most one wave takes this)
            for (int q = lane; q < F4_PER_WAVE; q += 64) {
                int idx = base + q;
                if (idx < n4) { floatv4 v = x4[idx]; BUMP4(v); }
            }
        }
    }
    if (blockIdx.x == 0) {             // scalar tail (n % 4)
        int tail = n & 3;
        if (tid < tail) { float v = x[(n4 << 2) + tid]; BUMP1(v); }
    }
    __syncthreads();

    const int wave = tid >> 6;

    // sigma weights in registers: sig_r[p] for j = 64p + lane (shared by all bins)
    float sig_r[10];
    #pragma unroll
    for (int p = 0; p < 10; ++p) {
        float z = (319.5f - (float)((p << 6) + lane)) * 0.0625f;
        sig_r[p] = 1.0f / (1.0f + __expf(-z));
    }

    // group sums: wave-parallel, conflict-free (64 consecutive cells per read)
    for (int g = wave; g < NGROUPS; g += HIST_THREADS / 64) {
        unsigned v = hist[(g << 6) + lane];
        #pragma unroll
        for (int o = 32; o; o >>= 1) v += __shfl_xor(v, o);
        if (lane == 0) G[g] = v;
    }
    __syncthreads();

    if (tid < NBINS) {                 // P[b] = count of cells f < 64*b
        unsigned p = 0;
        for (int g = 0; g < tid; ++g) p += G[g];
        P[tid] = p;
    }
    __syncthreads();

    // fold: wave w handles bins 16w..16w+15; lanes read consecutive cells
    #pragma unroll
    for (int bi = 0; bi < 16; ++bi) {
        const int b = (wave << 4) + bi;
        float ws = 0.0f;
        const int cbase = (b << 6) + lane;
        #pragma unroll
        for (int p = 0; p < 10; ++p)
            ws += (float)hist[cbase + (p << 6)] * sig_r[p];
        #pragma unroll
        for (int o = 32; o; o >>= 1) ws += __shfl_xor(ws, o);
        if (lane == 0)
            part[(b << 11) + blockIdx.x] = (double)P[b] + (double)ws;
    }
#undef BUMP1
#undef BUMP4
}

__global__ void __launch_bounds__(256)
finalize_kernel(const double* __restrict__ part,
                float* __restrict__ out, double invN)
{
    const int b = blockIdx.x;          // 64 blocks, one per output bin
    const int tid = threadIdx.x;
    double s = 0.0;
    for (int j = tid; j < HIST_BLOCKS; j += 256)
        s += part[(b << 11) + j];
    __shared__ double sd[256];
    sd[tid] = s;
    __syncthreads();
    for (int ofs = 128; ofs > 0; ofs >>= 1) {
        if (tid < ofs) sd[tid] += sd[tid + ofs];
        __syncthreads();
    }
    if (tid == 0) out[b] = (float)(sd[0] * invN);
}

extern "C" void kernel_launch(void* const* d_in, const int* in_sizes, int n_in,
                              void* d_out, int out_size, void* d_ws, size_t ws_size,
                              hipStream_t stream)
{
    const float* x = (const float*)d_in[0];
    const int n = in_sizes[0];
    double* part = (double*)d_ws;      // 64 bins x 2048 blocks x 8 B = 1 MB
    // part is fully overwritten by hist_fold_kernel each call -> no memset needed.

    hist_fold_kernel<<<HIST_BLOCKS, HIST_THREADS, 0, stream>>>(x, part, n);
    finalize_kernel<<<NBINS, 256, 0, stream>>>(part, (float*)d_out,
                                               1.0 / (double)n);
}